// Round 25
// baseline (88.670 us; speedup 1.0000x reference)
//
#include <hip/hip_runtime.h>

// ---------------- types & helpers (NO inline asm) ----------------
using short8 = __attribute__((ext_vector_type(8))) short;   // 8 x bf16 (4 VGPRs)
using f32x4  = __attribute__((ext_vector_type(4))) float;
using u16x4  = __attribute__((ext_vector_type(4))) unsigned short;

#define MFMA16(A,B,C) __builtin_amdgcn_mfma_f32_16x16x32_bf16((A),(B),(C),0,0,0)

#if __has_builtin(__builtin_amdgcn_exp2f)
#define EXP2(x) __builtin_amdgcn_exp2f(x)
#else
extern "C" __device__ float __ocml_native_exp2_f32(float);
#define EXP2(x) __ocml_native_exp2_f32(x)
#endif

__device__ __forceinline__ unsigned short f2b(float f) {
  unsigned u = __float_as_uint(f);
  return (unsigned short)((u + 0x7fffu + ((u >> 16) & 1u)) >> 16);  // RNE
}
__device__ __forceinline__ short8 mk8(unsigned a, unsigned b, unsigned c, unsigned d) {
  union { unsigned u[4]; short8 s; } t; t.u[0]=a; t.u[1]=b; t.u[2]=c; t.u[3]=d; return t.s;
}
// trunc-pack two f32 -> bf16x2 (1 VALU op; r12-proven with self-consistent ls)
__device__ __forceinline__ unsigned pk2(float lo, float hi) {
  return __builtin_amdgcn_perm(__float_as_uint(hi), __float_as_uint(lo), 0x07060302u);
}

// T=512, N=128, D=64, H=4, HID=OUT=64

// on-the-fly xin: bf16(x[t][n][d0..d0+7] + pe[...]) — EXACT prep computation
// (same f2b RNE per element) so all downstream values stay bit-identical.
// flat index for both x and pe: t*8192 + n*64 + d.
__device__ __forceinline__ short8 ldx8(const float* __restrict__ x,
                                       const float* __restrict__ pe,
                                       int nb, int t, int d0) {
  const f32x4* xa = (const f32x4*)(x  + t * 8192 + nb + d0);
  const f32x4* pa = (const f32x4*)(pe + t * 8192 + nb + d0);
  f32x4 a0 = xa[0], a1 = xa[1], p0 = pa[0], p1 = pa[1];
  short8 r;
  r[0]=(short)f2b(a0[0]+p0[0]); r[1]=(short)f2b(a0[1]+p0[1]);
  r[2]=(short)f2b(a0[2]+p0[2]); r[3]=(short)f2b(a0[3]+p0[3]);
  r[4]=(short)f2b(a1[0]+p1[0]); r[5]=(short)f2b(a1[1]+p1[1]);
  r[6]=(short)f2b(a1[2]+p1[2]); r[7]=(short)f2b(a1[3]+p1[3]);
  return r;
}

// ---------------- kernel 1: weight pre-pack only (xin round-trip eliminated) ----------------
__global__ void packw_kernel(const float* __restrict__ wq, const float* __restrict__ wk,
                             const float* __restrict__ wv, const float* __restrict__ wo,
                             unsigned short* __restrict__ wP) {
  int idx = blockIdx.x * 256 + threadIdx.x;   // 0 .. 65535
  int a = idx >> 14, e = idx & 16383;
  const float SC = 0.18033688011112042f;      // (1/sqrt(64)) * log2(e)
  float v = (a == 0) ? wq[e] * SC : (a == 1) ? wk[e] : (a == 2) ? wv[e] : wo[e];
  wP[idx] = f2b(v);
}

// ---------------- attn building blocks (r22-exact math, x/pe-direct reads) ----------------
__device__ __forceinline__ void qprojT(
    const float* x, const float* pe, int nb, const unsigned short* bqP, int qb16,
    int lg, int lm, short8 (&qB)[2]) {
  const f32x4 zero4 = {0.f, 0.f, 0.f, 0.f};
  short8 aX0 = ldx8(x, pe, nb, qb16 + lm, lg * 8);
  short8 aX1 = ldx8(x, pe, nb, qb16 + lm, 32 + lg * 8);
  f32x4 qt[4];
#pragma unroll
  for (int nt = 0; nt < 4; ++nt) {
    const unsigned short* p = bqP + (nt * 16 + lm) * 64 + lg * 8;
    short8 w0 = *(const short8*)p;
    short8 w1 = *(const short8*)(p + 32);
    f32x4 a = zero4;
    a = MFMA16(w0, aX0, a);
    a = MFMA16(w1, aX1, a);
    qt[nt] = a;
  }
#pragma unroll
  for (int ks = 0; ks < 2; ++ks) {
    short8 q;
#pragma unroll
    for (int i = 0; i < 8; ++i) q[i] = (short)f2b(qt[2 * ks + (i >> 2)][i & 3]);
    qB[ks] = q;
  }
}

// stage one 32-row slab of K (pi-layout + XOR swizzle) + V (kappa2) (r16-proven)
__device__ __forceinline__ void stage_slab(
    const float* x, const float* pe, int nb, int slab, int lg, int lm, int l,
    const unsigned short* bkP, const unsigned short* bvP,
    unsigned short* sK, short8* sVf) {
  const f32x4 zero4 = {0.f, 0.f, 0.f, 0.f};
  int s0 = slab * 32;
  short8 aX[2][2];
#pragma unroll
  for (int km = 0; km < 2; ++km) {
    aX[km][0] = ldx8(x, pe, nb, s0 + km * 16 + lm, lg * 8);
    aX[km][1] = ldx8(x, pe, nb, s0 + km * 16 + lm, 32 + lg * 8);
  }
#pragma unroll
  for (int nt = 0; nt < 4; ++nt) {
    const unsigned short* bko = bkP + (nt * 16 + lm) * 64 + lg * 8;
    const unsigned short* bvo = bvP + (nt * 16 + lm) * 64 + lg * 8;
    short8 wk0 = *(const short8*)bko, wk1 = *(const short8*)(bko + 32);
    short8 wv0 = *(const short8*)bvo, wv1 = *(const short8*)(bvo + 32);
    f32x4 k0 = zero4, k1 = zero4, v0 = zero4, v1 = zero4;
    k0 = MFMA16(aX[0][0], wk0, k0); k0 = MFMA16(aX[0][1], wk1, k0);
    k1 = MFMA16(aX[1][0], wk0, k1); k1 = MFMA16(aX[1][1], wk1, k1);
    v0 = MFMA16(aX[0][0], wv0, v0); v0 = MFMA16(aX[0][1], wv1, v0);
    v1 = MFMA16(aX[1][0], wv0, v1); v1 = MFMA16(aX[1][1], wv1, v1);
    int pos = ((nt & 2) << 4) + ((lm >> 2) << 3) + ((nt & 1) << 2) + (lm & 3);
#pragma unroll
    for (int r = 0; r < 4; ++r) {
      int row0 = s0 + lg * 4 + r;
      int row1 = s0 + 16 + lg * 4 + r;
      sK[row0 * 64 + (pos ^ ((row0 & 7) << 3))] = f2b(k0[r]);
      sK[row1 * 64 + (pos ^ ((row1 & 7) << 3))] = f2b(k1[r]);
    }
    short8 vv;
    vv[0]=(short)f2b(v0[0]); vv[1]=(short)f2b(v0[1]);
    vv[2]=(short)f2b(v0[2]); vv[3]=(short)f2b(v0[3]);
    vv[4]=(short)f2b(v1[0]); vv[5]=(short)f2b(v1[1]);
    vv[6]=(short)f2b(v1[2]); vv[7]=(short)f2b(v1[3]);
    sVf[(slab * 4 + nt) * 64 + l] = vv;
  }
}

__device__ __forceinline__ void load_vB(const short8* sVf, int kb, int l, short8 (&vB)[4]) {
#pragma unroll
  for (int ot = 0; ot < 4; ++ot) vB[ot] = sVf[(((kb >> 5) * 4) + ot) * 64 + l];
}

// one 32-key slab body (r22-exact)
__device__ __forceinline__ void slab_body(
    const unsigned short* sK, const short8 (&vB)[4], const short8 (&qB)[2][2],
    f32x4 (&oAcc)[2][4], f32x4 (&lsAcc)[2], const short8 ones,
    int qb, int kb, int lg, int lm) {
  const f32x4 zero4 = {0.f, 0.f, 0.f, 0.f};
  short8 aK[2][2];
#pragma unroll
  for (int km = 0; km < 2; ++km) {
    int row = kb + km * 16 + lm;
    int rb = row * 64, xorv = (row & 7) << 3;
    aK[km][0] = *(const short8*)&sK[rb + ((lg * 8) ^ xorv)];
    aK[km][1] = *(const short8*)&sK[rb + ((32 + lg * 8) ^ xorv)];
  }
  f32x4 st[2][2];
#pragma unroll
  for (int km = 0; km < 2; ++km)
#pragma unroll
    for (int qn = 0; qn < 2; ++qn) {
      f32x4 a = zero4;
      a = MFMA16(aK[km][0], qB[qn][0], a);
      a = MFMA16(aK[km][1], qB[qn][1], a);
      st[km][qn] = a;
    }
  if (kb == qb) {   // diagonal slab: causal mask -> exp2(-1e30) = 0
#pragma unroll
    for (int km = 0; km < 2; ++km)
#pragma unroll
      for (int qn = 0; qn < 2; ++qn) {
        if (km == 0 && qn == 1) continue;   // never masked
#pragma unroll
        for (int r = 0; r < 4; ++r) {
          int key = km * 16 + lg * 4 + r, qr = qn * 16 + lm;
          if (key > qr) st[km][qn][r] = -1e30f;
        }
      }
  }
#pragma unroll
  for (int km = 0; km < 2; ++km)
#pragma unroll
    for (int qn = 0; qn < 2; ++qn)
#pragma unroll
      for (int r = 0; r < 4; ++r) st[km][qn][r] = EXP2(st[km][qn][r]);
#pragma unroll
  for (int mo = 0; mo < 2; ++mo) {
    short8 pA = mk8(pk2(st[0][mo][0], st[0][mo][1]), pk2(st[0][mo][2], st[0][mo][3]),
                    pk2(st[1][mo][0], st[1][mo][1]), pk2(st[1][mo][2], st[1][mo][3]));
    lsAcc[mo] = MFMA16(ones, pA, lsAcc[mo]);   // ls[q=lm] in every reg
#pragma unroll
    for (int ot = 0; ot < 4; ++ot) oAcc[mo][ot] = MFMA16(vB[ot], pA, oAcc[mo][ot]);
  }
}

// ---------------- kernel 2: fused xin + QKV + causal flash attention ----------------
// r22 structure; xinT eliminated — x+pe read directly (same coalescing pattern,
// 4 h-blocks/n share the fp32 panel via L2/L3).
__global__ __launch_bounds__(512) void attn_kernel(
    const float* __restrict__ x, const float* __restrict__ pe,
    const unsigned short* __restrict__ wP,
    unsigned short* __restrict__ heads) {
  __shared__ unsigned short sK[512 * 64];   // 64 KiB, pi-layout + XOR swizzle
  __shared__ short8 sVf[16 * 4 * 64];       // 64 KiB kappa2 V fragments

  const int hn = blockIdx.x;
  const int h  = hn & 3;
  const int n  = hn >> 2;
  const int w  = threadIdx.x >> 6;    // 0..7
  const int l  = threadIdx.x & 63;
  const int lg = l >> 4;
  const int lm = l & 15;

  const int nb = n * 64;
  const f32x4 zero4 = {0.f, 0.f, 0.f, 0.f};
  const short8 ones = mk8(0x3F803F80u, 0x3F803F80u, 0x3F803F80u, 0x3F803F80u);

  const unsigned short* bqP = wP + h * 4096;
  const unsigned short* bkP = wP + 16384 + h * 4096;
  const unsigned short* bvP = wP + 32768 + h * 4096;

  // ---- stage all 512 K/V rows (wave w: slabs {2w, 2w+1}) ----
  stage_slab(x, pe, nb, w * 2,     lg, lm, l, bkP, bvP, sK, sVf);
  stage_slab(x, pe, nb, w * 2 + 1, lg, lm, l, bkP, bvP, sK, sVf);
  __syncthreads();   // the kernel's only barrier

  // ---- chunks {w, 15-w}: 32 rows each, 17 slab-steps/wave total ----
  for (int c = 0; c < 2; ++c) {
    const int chunk = c ? (15 - w) : w;
    const int qb = chunk * 32;

    short8 qB[2][2];   // [qn][ks]
    qprojT(x, pe, nb, bqP, qb,      lg, lm, qB[0]);
    qprojT(x, pe, nb, bqP, qb + 16, lg, lm, qB[1]);

    f32x4 oAcc[2][4];
#pragma unroll
    for (int mo = 0; mo < 2; ++mo)
#pragma unroll
      for (int ot = 0; ot < 4; ++ot) oAcc[mo][ot] = zero4;
    f32x4 lsAcc[2] = {zero4, zero4};

    // ---- pipelined slab loop: vB ping-pong (r19/r22-proven) ----
    short8 vA[4], vBv[4];
    load_vB(sVf, 0, l, vA);
    int kb = 0;
    while (true) {
      if (kb + 32 <= qb) load_vB(sVf, kb + 32, l, vBv);
      slab_body(sK, vA, qB, oAcc, lsAcc, ones, qb, kb, lg, lm);
      if (kb >= qb) break;
      kb += 32;
      if (kb + 32 <= qb) load_vB(sVf, kb + 32, l, vA);
      slab_body(sK, vBv, qB, oAcc, lsAcc, ones, qb, kb, lg, lm);
      if (kb >= qb) break;
      kb += 32;
    }

    // ---- direct store: lane (lg,lm) owns t=qb+mo*16+lm, o=ot*16+4lg+r ----
#pragma unroll
    for (int mo = 0; mo < 2; ++mo) {
      float li = 1.0f / lsAcc[mo][0];
      unsigned short* base = heads + ((qb + mo * 16 + lm) * 128 + n) * 256 + h * 64 + lg * 4;
#pragma unroll
      for (int ot = 0; ot < 4; ++ot) {
        u16x4 v;
#pragma unroll
        for (int r = 0; r < 4; ++r) v[r] = f2b(oAcc[mo][ot][r] * li);
        *(u16x4*)(base + ot * 16) = v;
      }
    }
  }
}

// ---------------- kernel 3: out = heads[65536,256] @ wo^T (r22-exact) ----------------
__global__ __launch_bounds__(256) void outproj_kernel(
    const unsigned short* __restrict__ heads,
    const unsigned short* __restrict__ woP,
    float* __restrict__ out) {
  const int w  = threadIdx.x >> 6;
  const int l  = threadIdx.x & 63;
  const int lg = l >> 4, lm = l & 15;
  const f32x4 zero4 = {0.f, 0.f, 0.f, 0.f};

  short8 woB[4][8];
#pragma unroll
  for (int nt = 0; nt < 4; ++nt)
#pragma unroll
    for (int ks = 0; ks < 8; ++ks)
      woB[nt][ks] = *(const short8*)(woP + (nt * 16 + lm) * 256 + ks * 32 + lg * 8);

  const int wid = blockIdx.x * 4 + w;
  for (int it = 0; it < 2; ++it) {
    int r0 = (wid * 2 + it) * 16;
    f32x4 acc[4];
#pragma unroll
    for (int nt = 0; nt < 4; ++nt) acc[nt] = zero4;
#pragma unroll
    for (int ks = 0; ks < 8; ++ks) {
      short8 aF = *(const short8*)&heads[(r0 + lm) * 256 + ks * 32 + lg * 8];
#pragma unroll
      for (int nt = 0; nt < 4; ++nt)
        acc[nt] = MFMA16(aF, woB[nt][ks], acc[nt]);
    }
#pragma unroll
    for (int nt = 0; nt < 4; ++nt)
#pragma unroll
      for (int r = 0; r < 4; ++r)
        out[(r0 + lg * 4 + r) * 64 + nt * 16 + lm] = acc[nt][r];
  }
}

// ---------------- launch ----------------
extern "C" void kernel_launch(void* const* d_in, const int* in_sizes, int n_in,
                              void* d_out, int out_size, void* d_ws, size_t ws_size,
                              hipStream_t stream) {
  const float* x  = (const float*)d_in[0];
  const float* pe = (const float*)d_in[1];
  const float* wq = (const float*)d_in[2];
  const float* wk = (const float*)d_in[3];
  const float* wv = (const float*)d_in[4];
  const float* wo = (const float*)d_in[5];

  // ws: heads 32 MiB @16 MiB, packed weights 128 KiB @48 MiB (proven offsets)
  unsigned short* heads = (unsigned short*)((char*)d_ws + (16u << 20));
  unsigned short* wPk   = (unsigned short*)((char*)d_ws + (48u << 20));

  packw_kernel<<<256, 256, 0, stream>>>(wq, wk, wv, wo, wPk);
  attn_kernel<<<512, 512, 0, stream>>>(x, pe, wPk, heads);
  outproj_kernel<<<512, 256, 0, stream>>>(heads, wPk + 49152, (float*)d_out);
}

// Round 26
// 68.446 us; speedup vs baseline: 1.2955x; 1.2955x over previous
//
#include <hip/hip_runtime.h>

// ---------------- types & helpers (NO inline asm) ----------------
using short8 = __attribute__((ext_vector_type(8))) short;   // 8 x bf16 (4 VGPRs)
using f32x4  = __attribute__((ext_vector_type(4))) float;
using u16x4  = __attribute__((ext_vector_type(4))) unsigned short;

#define MFMA16(A,B,C) __builtin_amdgcn_mfma_f32_16x16x32_bf16((A),(B),(C),0,0,0)

#if __has_builtin(__builtin_amdgcn_exp2f)
#define EXP2(x) __builtin_amdgcn_exp2f(x)
#else
extern "C" __device__ float __ocml_native_exp2_f32(float);
#define EXP2(x) __ocml_native_exp2_f32(x)
#endif

__device__ __forceinline__ unsigned short f2b(float f) {
  unsigned u = __float_as_uint(f);
  return (unsigned short)((u + 0x7fffu + ((u >> 16) & 1u)) >> 16);  // RNE
}
__device__ __forceinline__ short8 mk8(unsigned a, unsigned b, unsigned c, unsigned d) {
  union { unsigned u[4]; short8 s; } t; t.u[0]=a; t.u[1]=b; t.u[2]=c; t.u[3]=d; return t.s;
}
// trunc-pack two f32 -> bf16x2 (1 VALU op; r12-proven with self-consistent ls)
__device__ __forceinline__ unsigned pk2(float lo, float hi) {
  return __builtin_amdgcn_perm(__float_as_uint(hi), __float_as_uint(lo), 0x07060302u);
}

// T=512, N=128, D=64, H=4, HID=OUT=64

// ---------------- kernel 1: prep (x+pe -> xinT bf16) + weight pre-pack ----------------
// Staged xinT is deliberate: bf16 halves the bytes and reads are full-line
// coalesced; fusing x+pe into attn (r25) caused 4x line over-fetch (126 MB).
__global__ void prep_kernel(const float* __restrict__ x, const float* __restrict__ pe,
                            unsigned* __restrict__ xinT,
                            const float* __restrict__ wq, const float* __restrict__ wk,
                            const float* __restrict__ wv, const float* __restrict__ wo,
                            unsigned short* __restrict__ wP) {
  int b = blockIdx.x;
  if (b >= 8192) {
    int idx = (b - 8192) * 256 + threadIdx.x;   // 0 .. 65535
    int a = idx >> 14, e = idx & 16383;
    const float SC = 0.18033688011112042f;      // (1/sqrt(64)) * log2(e)
    float v = (a == 0) ? wq[e] * SC : (a == 1) ? wk[e] : (a == 2) ? wv[e] : wo[e];
    wP[idx] = f2b(v);
    return;
  }
  int i2 = b * 256 + threadIdx.x;
  const float2* xp = (const float2*)x;
  const float2* pp = (const float2*)pe;
  float2 a = xp[i2], c = pp[i2];
  float s0 = a.x + c.x, s1 = a.y + c.y;
  int i = i2 << 1;
  int t = i >> 13, rem = i & 8191, n = rem >> 6, d = rem & 63;
  unsigned v = (unsigned)f2b(s0) | ((unsigned)f2b(s1) << 16);
  xinT[((n * 512 + t) * 64 + d) >> 1] = v;
}

// ---------------- attn building blocks (r22/r24-exact) ----------------
// LDS-free Q^T projection (r15-proven; pre-packed bf16 weights)
__device__ __forceinline__ void qprojT(
    const unsigned short* xn, const unsigned short* bqP, int qb16,
    int lg, int lm, short8 (&qB)[2]) {
  const f32x4 zero4 = {0.f, 0.f, 0.f, 0.f};
  short8 aX0 = *(const short8*)(xn + (qb16 + lm) * 64 + lg * 8);
  short8 aX1 = *(const short8*)(xn + (qb16 + lm) * 64 + 32 + lg * 8);
  f32x4 qt[4];
#pragma unroll
  for (int nt = 0; nt < 4; ++nt) {
    const unsigned short* p = bqP + (nt * 16 + lm) * 64 + lg * 8;
    short8 w0 = *(const short8*)p;
    short8 w1 = *(const short8*)(p + 32);
    f32x4 a = zero4;
    a = MFMA16(w0, aX0, a);
    a = MFMA16(w1, aX1, a);
    qt[nt] = a;
  }
#pragma unroll
  for (int ks = 0; ks < 2; ++ks) {
    short8 q;
#pragma unroll
    for (int i = 0; i < 8; ++i) q[i] = (short)f2b(qt[2 * ks + (i >> 2)][i & 3]);
    qB[ks] = q;
  }
}

// stage one 32-row slab of K (pi-layout + XOR swizzle) + V (kappa2) (r16-proven)
__device__ __forceinline__ void stage_slab(
    const unsigned short* xn, int slab, int lg, int lm, int l,
    const unsigned short* bkP, const unsigned short* bvP,
    unsigned short* sK, short8* sVf) {
  const f32x4 zero4 = {0.f, 0.f, 0.f, 0.f};
  int s0 = slab * 32;
  short8 aX[2][2];
#pragma unroll
  for (int km = 0; km < 2; ++km) {
    aX[km][0] = *(const short8*)(xn + (s0 + km * 16 + lm) * 64 + lg * 8);
    aX[km][1] = *(const short8*)(xn + (s0 + km * 16 + lm) * 64 + 32 + lg * 8);
  }
#pragma unroll
  for (int nt = 0; nt < 4; ++nt) {
    const unsigned short* bko = bkP + (nt * 16 + lm) * 64 + lg * 8;
    const unsigned short* bvo = bvP + (nt * 16 + lm) * 64 + lg * 8;
    short8 wk0 = *(const short8*)bko, wk1 = *(const short8*)(bko + 32);
    short8 wv0 = *(const short8*)bvo, wv1 = *(const short8*)(bvo + 32);
    f32x4 k0 = zero4, k1 = zero4, v0 = zero4, v1 = zero4;
    k0 = MFMA16(aX[0][0], wk0, k0); k0 = MFMA16(aX[0][1], wk1, k0);
    k1 = MFMA16(aX[1][0], wk0, k1); k1 = MFMA16(aX[1][1], wk1, k1);
    v0 = MFMA16(aX[0][0], wv0, v0); v0 = MFMA16(aX[0][1], wv1, v0);
    v1 = MFMA16(aX[1][0], wv0, v1); v1 = MFMA16(aX[1][1], wv1, v1);
    int pos = ((nt & 2) << 4) + ((lm >> 2) << 3) + ((nt & 1) << 2) + (lm & 3);
#pragma unroll
    for (int r = 0; r < 4; ++r) {
      int row0 = s0 + lg * 4 + r;
      int row1 = s0 + 16 + lg * 4 + r;
      sK[row0 * 64 + (pos ^ ((row0 & 7) << 3))] = f2b(k0[r]);
      sK[row1 * 64 + (pos ^ ((row1 & 7) << 3))] = f2b(k1[r]);
    }
    short8 vv;
    vv[0]=(short)f2b(v0[0]); vv[1]=(short)f2b(v0[1]);
    vv[2]=(short)f2b(v0[2]); vv[3]=(short)f2b(v0[3]);
    vv[4]=(short)f2b(v1[0]); vv[5]=(short)f2b(v1[1]);
    vv[6]=(short)f2b(v1[2]); vv[7]=(short)f2b(v1[3]);
    sVf[(slab * 4 + nt) * 64 + l] = vv;
  }
}

__device__ __forceinline__ void load_vB(const short8* sVf, int kb, int l, short8 (&vB)[4]) {
#pragma unroll
  for (int ot = 0; ot < 4; ++ot) vB[ot] = sVf[(((kb >> 5) * 4) + ot) * 64 + l];
}

// one 32-key slab body (r22-exact: aK loaded in-body, vB preloaded)
__device__ __forceinline__ void slab_body(
    const unsigned short* sK, const short8 (&vB)[4], const short8 (&qB)[2][2],
    f32x4 (&oAcc)[2][4], f32x4 (&lsAcc)[2], const short8 ones,
    int qb, int kb, int lg, int lm) {
  const f32x4 zero4 = {0.f, 0.f, 0.f, 0.f};
  short8 aK[2][2];
#pragma unroll
  for (int km = 0; km < 2; ++km) {
    int row = kb + km * 16 + lm;
    int rb = row * 64, xorv = (row & 7) << 3;
    aK[km][0] = *(const short8*)&sK[rb + ((lg * 8) ^ xorv)];
    aK[km][1] = *(const short8*)&sK[rb + ((32 + lg * 8) ^ xorv)];
  }
  f32x4 st[2][2];
#pragma unroll
  for (int km = 0; km < 2; ++km)
#pragma unroll
    for (int qn = 0; qn < 2; ++qn) {
      f32x4 a = zero4;
      a = MFMA16(aK[km][0], qB[qn][0], a);
      a = MFMA16(aK[km][1], qB[qn][1], a);
      st[km][qn] = a;
    }
  if (kb == qb) {   // diagonal slab: causal mask -> exp2(-1e30) = 0
#pragma unroll
    for (int km = 0; km < 2; ++km)
#pragma unroll
      for (int qn = 0; qn < 2; ++qn) {
        if (km == 0 && qn == 1) continue;   // never masked
#pragma unroll
        for (int r = 0; r < 4; ++r) {
          int key = km * 16 + lg * 4 + r, qr = qn * 16 + lm;
          if (key > qr) st[km][qn][r] = -1e30f;
        }
      }
  }
#pragma unroll
  for (int km = 0; km < 2; ++km)
#pragma unroll
    for (int qn = 0; qn < 2; ++qn)
#pragma unroll
      for (int r = 0; r < 4; ++r) st[km][qn][r] = EXP2(st[km][qn][r]);
#pragma unroll
  for (int mo = 0; mo < 2; ++mo) {
    short8 pA = mk8(pk2(st[0][mo][0], st[0][mo][1]), pk2(st[0][mo][2], st[0][mo][3]),
                    pk2(st[1][mo][0], st[1][mo][1]), pk2(st[1][mo][2], st[1][mo][3]));
    lsAcc[mo] = MFMA16(ones, pA, lsAcc[mo]);   // ls[q=lm] in every reg
#pragma unroll
    for (int ot = 0; ot < 4; ++ot) oAcc[mo][ot] = MFMA16(vB[ot], pA, oAcc[mo][ot]);
  }
}

// ---------------- kernel 2: fused QKV + causal flash attention (r24-exact) ----------------
__global__ __launch_bounds__(512) void attn_kernel(
    const unsigned short* __restrict__ xinT,
    const unsigned short* __restrict__ wP,
    unsigned short* __restrict__ heads) {
  __shared__ unsigned short sK[512 * 64];   // 64 KiB, pi-layout + XOR swizzle
  __shared__ short8 sVf[16 * 4 * 64];       // 64 KiB kappa2 V fragments

  const int hn = blockIdx.x;
  const int h  = hn & 3;
  const int n  = hn >> 2;
  const int w  = threadIdx.x >> 6;    // 0..7
  const int l  = threadIdx.x & 63;
  const int lg = l >> 4;
  const int lm = l & 15;

  const unsigned short* xn = xinT + n * (512 * 64);
  const f32x4 zero4 = {0.f, 0.f, 0.f, 0.f};
  const short8 ones = mk8(0x3F803F80u, 0x3F803F80u, 0x3F803F80u, 0x3F803F80u);

  const unsigned short* bqP = wP + h * 4096;
  const unsigned short* bkP = wP + 16384 + h * 4096;
  const unsigned short* bvP = wP + 32768 + h * 4096;

  // ---- stage all 512 K/V rows (wave w: slabs {2w, 2w+1}) ----
  stage_slab(xn, w * 2,     lg, lm, l, bkP, bvP, sK, sVf);
  stage_slab(xn, w * 2 + 1, lg, lm, l, bkP, bvP, sK, sVf);
  __syncthreads();   // the kernel's only barrier

  // ---- chunks {w, 15-w}: 32 rows each, 17 slab-steps/wave total ----
  for (int c = 0; c < 2; ++c) {
    const int chunk = c ? (15 - w) : w;
    const int qb = chunk * 32;

    short8 qB[2][2];   // [qn][ks]
    qprojT(xn, bqP, qb,      lg, lm, qB[0]);
    qprojT(xn, bqP, qb + 16, lg, lm, qB[1]);

    f32x4 oAcc[2][4];
#pragma unroll
    for (int mo = 0; mo < 2; ++mo)
#pragma unroll
      for (int ot = 0; ot < 4; ++ot) oAcc[mo][ot] = zero4;
    f32x4 lsAcc[2] = {zero4, zero4};

    // ---- pipelined slab loop: vB ping-pong (r19/r22-proven) ----
    short8 vA[4], vBv[4];
    load_vB(sVf, 0, l, vA);
    int kb = 0;
    while (true) {
      if (kb + 32 <= qb) load_vB(sVf, kb + 32, l, vBv);
      slab_body(sK, vA, qB, oAcc, lsAcc, ones, qb, kb, lg, lm);
      if (kb >= qb) break;
      kb += 32;
      if (kb + 32 <= qb) load_vB(sVf, kb + 32, l, vA);
      slab_body(sK, vBv, qB, oAcc, lsAcc, ones, qb, kb, lg, lm);
      if (kb >= qb) break;
      kb += 32;
    }

    // ---- direct store: lane (lg,lm) owns t=qb+mo*16+lm, o=ot*16+4lg+r ----
#pragma unroll
    for (int mo = 0; mo < 2; ++mo) {
      float li = 1.0f / lsAcc[mo][0];
      unsigned short* base = heads + ((qb + mo * 16 + lm) * 128 + n) * 256 + h * 64 + lg * 4;
#pragma unroll
      for (int ot = 0; ot < 4; ++ot) {
        u16x4 v;
#pragma unroll
        for (int r = 0; r < 4; ++r) v[r] = f2b(oAcc[mo][ot][r] * li);
        *(u16x4*)(base + ot * 16) = v;
      }
    }
  }
}

// ---------------- kernel 3: out = heads[65536,256] @ wo^T (r24-exact) ----------------
__global__ __launch_bounds__(256) void outproj_kernel(
    const unsigned short* __restrict__ heads,
    const unsigned short* __restrict__ woP,
    float* __restrict__ out) {
  const int w  = threadIdx.x >> 6;
  const int l  = threadIdx.x & 63;
  const int lg = l >> 4, lm = l & 15;
  const f32x4 zero4 = {0.f, 0.f, 0.f, 0.f};

  short8 woB[4][8];
#pragma unroll
  for (int nt = 0; nt < 4; ++nt)
#pragma unroll
    for (int ks = 0; ks < 8; ++ks)
      woB[nt][ks] = *(const short8*)(woP + (nt * 16 + lm) * 256 + ks * 32 + lg * 8);

  const int wid = blockIdx.x * 4 + w;
  for (int it = 0; it < 2; ++it) {
    int r0 = (wid * 2 + it) * 16;
    f32x4 acc[4];
#pragma unroll
    for (int nt = 0; nt < 4; ++nt) acc[nt] = zero4;
#pragma unroll
    for (int ks = 0; ks < 8; ++ks) {
      short8 aF = *(const short8*)&heads[(r0 + lm) * 256 + ks * 32 + lg * 8];
#pragma unroll
      for (int nt = 0; nt < 4; ++nt)
        acc[nt] = MFMA16(aF, woB[nt][ks], acc[nt]);
    }
#pragma unroll
    for (int nt = 0; nt < 4; ++nt)
#pragma unroll
      for (int r = 0; r < 4; ++r)
        out[(r0 + lg * 4 + r) * 64 + nt * 16 + lm] = acc[nt][r];
  }
}

// ---------------- launch (r24-exact) ----------------
extern "C" void kernel_launch(void* const* d_in, const int* in_sizes, int n_in,
                              void* d_out, int out_size, void* d_ws, size_t ws_size,
                              hipStream_t stream) {
  const float* x  = (const float*)d_in[0];
  const float* pe = (const float*)d_in[1];
  const float* wq = (const float*)d_in[2];
  const float* wk = (const float*)d_in[3];
  const float* wv = (const float*)d_in[4];
  const float* wo = (const float*)d_in[5];

  // ws: xinT 8 MiB @0, heads 32 MiB @16 MiB, packed weights 128 KiB @48 MiB
  unsigned short* xinT  = (unsigned short*)d_ws;
  unsigned short* heads = (unsigned short*)((char*)d_ws + (16u << 20));
  unsigned short* wPk   = (unsigned short*)((char*)d_ws + (48u << 20));

  prep_kernel<<<8448, 256, 0, stream>>>(x, pe, (unsigned*)xinT, wq, wk, wv, wo, wPk);
  attn_kernel<<<512, 512, 0, stream>>>(xinT, wPk, heads);
  outproj_kernel<<<512, 256, 0, stream>>>(heads, wPk + 49152, (float*)d_out);
}